// Round 6
// baseline (273.413 us; speedup 1.0000x reference)
//
#include <hip/hip_runtime.h>

// GraphSAGE encoder on MI355X.
// CSR build via 2-level bucketing (high-occupancy histogram, convoy-ordered
// adjacency) -> mean-aggregate (16B/lane, 8-deep-ILP gathers) -> dense via
// split-bf16 MFMA (A@B ~= Ah@Bh + Al@Bh + Ah@Bl, fp32-equivalent accuracy).

typedef unsigned short ushort_t;
typedef unsigned int uint_t;
typedef __attribute__((ext_vector_type(8))) short short8;
typedef __attribute__((ext_vector_type(8))) ushort_t ushort8;
typedef __attribute__((ext_vector_type(4))) float f32x4;

#define BKT_SHIFT 7            // 128 nodes per bucket
#define BKT_NODES 128
#define BKT_CAP   5120         // mean 4092 + 16 sigma headroom
#define EPB       4096         // edges per block in bucket-scatter
#define SCH_SHIFT 13           // src-chunk = src>>13 (2MB feature windows)
#define SCH_N     8            // max chunks (50000>>13 = 6 -> 7 used)

// ---------------- bf16 helpers ----------------

__device__ inline ushort_t bf16_rne(float v) {
    uint_t u = __float_as_uint(v);
    u += 0x7fffu + ((u >> 16) & 1u);
    return (ushort_t)(u >> 16);
}
__device__ inline float bf16_to_f(ushort_t h) {
    return __uint_as_float((uint_t)h << 16);
}

// ---------------- CSR build ----------------
// phase 1: bucket edges by dst>>7. 1024 threads/block (6256 waves device-wide),
// 4 lane-interleaved sub-histograms, one int4 edge load reused in both passes.

__global__ __launch_bounds__(1024) void k_bucket(const int* __restrict__ src,
                                                 const int* __restrict__ dst,
                                                 uint_t* __restrict__ pairs,
                                                 int* __restrict__ bcnt,
                                                 int E, int nbk) {
    __shared__ int h[4][512];
    int tid = threadIdx.x;
    int sub = tid & 3;
    for (int i = tid; i < 4 * 512; i += 1024) ((int*)h)[i] = 0;
    __syncthreads();

    int e = blockIdx.x * EPB + tid * 4;
    bool full = (e + 4 <= E);
    int4 d4 = {0, 0, 0, 0}, s4 = {0, 0, 0, 0};
    if (full) {
        d4 = *(const int4*)(dst + e);
        s4 = *(const int4*)(src + e);
        atomicAdd(&h[sub][d4.x >> BKT_SHIFT], 1);
        atomicAdd(&h[sub][d4.y >> BKT_SHIFT], 1);
        atomicAdd(&h[sub][d4.z >> BKT_SHIFT], 1);
        atomicAdd(&h[sub][d4.w >> BKT_SHIFT], 1);
    } else {
        for (int t = e; t < E && t < e + 4; ++t)
            atomicAdd(&h[sub][dst[t] >> BKT_SHIFT], 1);
    }
    __syncthreads();
    for (int i = tid; i < nbk; i += 1024) {
        int c0 = h[0][i], c1 = h[1][i], c2 = h[2][i], c3 = h[3][i];
        int c = c0 + c1 + c2 + c3;
        int bs = c ? atomicAdd(&bcnt[i], c) : 0;
        h[0][i] = bs; h[1][i] = bs + c0; h[2][i] = bs + c0 + c1;
        h[3][i] = bs + c0 + c1 + c2;
    }
    __syncthreads();
    if (full) {
        int dd[4] = {d4.x, d4.y, d4.z, d4.w};
        int ss[4] = {s4.x, s4.y, s4.z, s4.w};
#pragma unroll
        for (int t = 0; t < 4; ++t) {
            int b = dd[t] >> BKT_SHIFT;
            int r = atomicAdd(&h[sub][b], 1);
            pairs[(size_t)b * BKT_CAP + r] =
                (uint_t)(ss[t] & 0xFFFF) | ((uint_t)(dd[t] & (BKT_NODES - 1)) << 16);
        }
    } else {
        for (int t = e; t < E && t < e + 4; ++t) {
            int d = dst[t];
            int b = d >> BKT_SHIFT;
            int r = atomicAdd(&h[sub][b], 1);
            pairs[(size_t)b * BKT_CAP + r] =
                (uint_t)(src[t] & 0xFFFF) | ((uint_t)(d & (BKT_NODES - 1)) << 16);
        }
    }
}

// phase 2: tiny single-block scan of 391 bucket counts -> bucket offsets
__global__ void k_bscan(const int* __restrict__ bcnt, int* __restrict__ boff,
                        int nbk) {
    __shared__ int s[512];
    int tid = threadIdx.x;
    int v = (tid < nbk) ? bcnt[tid] : 0;
    s[tid] = v;
    __syncthreads();
    for (int ofs = 1; ofs < 512; ofs <<= 1) {
        int t = (tid >= ofs) ? s[tid - ofs] : 0;
        __syncthreads();
        s[tid] += t;
        __syncthreads();
    }
    if (tid < nbk) boff[tid] = s[tid] - v;   // exclusive
}

// phase 3 (fused): per-bucket histogram over (local, src-chunk) keys + LDS
// scan + off write + fine scatter. Keying by src-chunk makes each node's
// adjacency list ascend through 2MB feature windows -> all waves gather from
// a moving L2-resident window during aggregation (convoy effect).
__global__ __launch_bounds__(512) void k_csr(const uint_t* __restrict__ pairs,
                                             const int* __restrict__ bcnt,
                                             const int* __restrict__ boff,
                                             int* __restrict__ off,
                                             ushort_t* __restrict__ col, int n) {
    __shared__ int hist[BKT_NODES * SCH_N];   // 1024 keys
    __shared__ int cur[BKT_NODES * SCH_N];
    __shared__ int ss[512];
    int b = blockIdx.x, tid = threadIdx.x;
    hist[tid] = 0; hist[tid + 512] = 0;
    __syncthreads();
    int cnt = bcnt[b];
    const uint_t* p = pairs + (size_t)b * BKT_CAP;
    for (int i = tid; i < cnt; i += 512) {
        uint_t u = p[i];
        int key = (int)(((u >> 16) & 127) << 3) | (int)((u & 0xFFFF) >> SCH_SHIFT);
        atomicAdd(&hist[key], 1);
    }
    __syncthreads();
    // pair-wise blocked scan of 1024 keys with 512 threads
    int v0 = hist[2 * tid], v1 = hist[2 * tid + 1];
    int sv = v0 + v1;
    ss[tid] = sv;
    __syncthreads();
    for (int ofs = 1; ofs < 512; ofs <<= 1) {
        int t = (tid >= ofs) ? ss[tid - ofs] : 0;
        __syncthreads();
        ss[tid] += t;
        __syncthreads();
    }
    int excl = boff[b] + ss[tid] - sv;
    cur[2 * tid] = excl;
    cur[2 * tid + 1] = excl + v0;
    __syncthreads();
    if (tid < BKT_NODES) {
        int node = b * BKT_NODES + tid;
        if (node <= n) off[node] = cur[tid << 3];   // key (local, chunk 0)
    }
    __syncthreads();
    for (int i = tid; i < cnt; i += 512) {
        uint_t u = p[i];
        int key = (int)(((u >> 16) & 127) << 3) | (int)((u & 0xFFFF) >> SCH_SHIFT);
        int pos = atomicAdd(&cur[key], 1);
        col[pos] = (ushort_t)(u & 0xFFFF);
    }
}

// ---------------- input split / fused weight pack ----------------

__global__ void k_split(const float* __restrict__ x, ushort_t* __restrict__ xh,
                        ushort_t* __restrict__ xl, int total) {
    int t = blockIdx.x * blockDim.x + threadIdx.x;
    if (t < total) {
        float v = x[t];
        ushort_t h = bf16_rne(v);
        xh[t] = h;
        xl[t] = bf16_rne(v - bf16_to_f(h));
    }
}

struct WPack {
    const float* srcp[5];
    ushort_t* dstp[5];
    int K[5], N[5], beg[5], end[5];
};

// Pack W (K x N row-major fp32) into MFMA B-fragment order, hi then lo:
// dst[hl][kt][nt][lane][j], lane=(k/8%4)*16+(n%16), j=k%8.
__global__ void k_pack_all(WPack wp, int total) {
    int t = blockIdx.x * blockDim.x + threadIdx.x;
    if (t >= total) return;
#pragma unroll
    for (int m = 0; m < 5; ++m) {
        if (t >= wp.beg[m] && t < wp.end[m]) {
            int i = t - wp.beg[m];
            int K = wp.K[m], N = wp.N[m];
            int k = i / N, nn = i % N;
            int KT = K >> 5, NT = N >> 4;
            int kt = k >> 5, bq = (k >> 3) & 3, j = k & 7;
            int nt = nn >> 4, lane = (bq << 4) | (nn & 15);
            int base = (((kt * NT + nt) << 6) + lane) * 8 + j;
            int halfsz = KT * NT * 512;
            float v = wp.srcp[m][i];
            ushort_t h = bf16_rne(v);
            wp.dstp[m][base] = h;
            wp.dstp[m][halfsz + base] = bf16_rne(v - bf16_to_f(h));
        }
    }
}

// ---------------- mean aggregation ----------------
// One wave per node. 16B/lane packed-bf16 gathers, LPR lanes/row, EPI edges
// per instruction. Full chunks: DEEP independent gathers in flight, unmasked
// float2 adds. Masked 4-deep tail rounds. shfl_xor butterfly.

__device__ inline void accum2(float2 (&a)[4], uint4 q) {
    const uint_t* u = (const uint_t*)&q;
#pragma unroll
    for (int i = 0; i < 4; ++i) {
        a[i].x += __uint_as_float(u[i] << 16);
        a[i].y += __uint_as_float(u[i] & 0xffff0000u);
    }
}
__device__ inline void accum2m(float2 (&a)[4], uint4 q, float m) {
    const uint_t* u = (const uint_t*)&q;
#pragma unroll
    for (int i = 0; i < 4; ++i) {
        a[i].x = fmaf(m, __uint_as_float(u[i] << 16), a[i].x);
        a[i].y = fmaf(m, __uint_as_float(u[i] & 0xffff0000u), a[i].y);
    }
}

template <int DIN>
__global__ __launch_bounds__(256) void k_agg(const ushort_t* __restrict__ fh,
                                             const int* __restrict__ off,
                                             const ushort_t* __restrict__ col,
                                             ushort_t* __restrict__ ah,
                                             ushort_t* __restrict__ al, int n) {
    constexpr int LPR = DIN / 8;       // lanes per row: 8 (D64) / 16 (D128)
    constexpr int EPI = 64 / LPR;      // edges per instruction: 8 / 4
    constexpr int DEEP = (DIN == 128) ? 8 : 4;   // gathers in flight
    int wave = (int)((blockIdx.x * (unsigned)blockDim.x + threadIdx.x) >> 6);
    int lane = threadIdx.x & 63;
    if (wave >= n) return;
    int li = lane & (LPR - 1);         // column slice
    int sub = lane / LPR;              // edge slot
    int s0 = off[wave], s1 = off[wave + 1];
    float2 a2[4] = {{0.f, 0.f}, {0.f, 0.f}, {0.f, 0.f}, {0.f, 0.f}};
    const ushort_t* __restrict__ fbase = fh + li * 8;

    int e = s0;
    // full chunks: DEEP*EPI edges, DEEP independent gathers, no masks
    for (; e + DEEP * EPI <= s1; e += DEEP * EPI) {
        int c[DEEP];
        uint4 q[DEEP];
#pragma unroll
        for (int j = 0; j < DEEP; ++j) c[j] = col[e + j * EPI + sub];
#pragma unroll
        for (int j = 0; j < DEEP; ++j) q[j] = *(const uint4*)(fbase + (size_t)c[j] * DIN);
#pragma unroll
        for (int j = 0; j < DEEP; ++j) accum2(a2, q[j]);
    }
    // masked 4-deep tail rounds
    for (; e < s1; e += 4 * EPI) {
        int last = s1 - 1;
        int i0 = e + sub, i1 = i0 + EPI, i2 = i1 + EPI, i3 = i2 + EPI;
        float m0 = (i0 < s1) ? 1.f : 0.f;
        float m1 = (i1 < s1) ? 1.f : 0.f;
        float m2 = (i2 < s1) ? 1.f : 0.f;
        float m3 = (i3 < s1) ? 1.f : 0.f;
        int c0 = col[min(i0, last)];
        int c1 = col[min(i1, last)];
        int c2 = col[min(i2, last)];
        int c3 = col[min(i3, last)];
        uint4 q0 = *(const uint4*)(fbase + (size_t)c0 * DIN);
        uint4 q1 = *(const uint4*)(fbase + (size_t)c1 * DIN);
        uint4 q2 = *(const uint4*)(fbase + (size_t)c2 * DIN);
        uint4 q3 = *(const uint4*)(fbase + (size_t)c3 * DIN);
        accum2m(a2, q0, m0); accum2m(a2, q1, m1);
        accum2m(a2, q2, m2); accum2m(a2, q3, m3);
    }
    // combine edge slots
#pragma unroll
    for (int m = LPR; m < 64; m <<= 1) {
#pragma unroll
        for (int j = 0; j < 4; ++j) {
            a2[j].x += __shfl_xor(a2[j].x, m);
            a2[j].y += __shfl_xor(a2[j].y, m);
        }
    }
    if (sub == 0) {
        float inv = 1.f / fmaxf((float)(s1 - s0), 1.f);
        ushort8 vh, vl;
#pragma unroll
        for (int j = 0; j < 4; ++j) {
            float mx = a2[j].x * inv;
            float my = a2[j].y * inv;
            ushort_t hx = bf16_rne(mx), hy = bf16_rne(my);
            vh[2 * j] = hx;     vl[2 * j] = bf16_rne(mx - bf16_to_f(hx));
            vh[2 * j + 1] = hy; vl[2 * j + 1] = bf16_rne(my - bf16_to_f(hy));
        }
        *(ushort8*)(ah + (size_t)wave * DIN + li * 8) = vh;
        *(ushort8*)(al + (size_t)wave * DIN + li * 8) = vl;
    }
}

// ---------------- MFMA dense ----------------
// acc += (Fh+Fl) @ (Wh+Wl) via 3 MFMA products per tile.
// A-frag: 16B contiguous loads from row-major bf16. B-frag: prepacked,
// lane-indexed 16B loads (L1/L2-hot). C/D: col=lane&15, row=(lane>>4)*4+reg.

template <int DIN, int DOUT, int M2>
__device__ inline void mfma_pass(const ushort_t* __restrict__ Fh,
                                 const ushort_t* __restrict__ Fl,
                                 const ushort_t* __restrict__ Wp,
                                 f32x4 (&acc)[M2][DOUT / 16],
                                 int base, int n, int lane) {
    constexpr int KT = DIN / 32, NT = DOUT / 16;
    int col = lane & 15, quad = lane >> 4;
    short8 fh[M2][KT], fl[M2][KT];
#pragma unroll
    for (int c = 0; c < M2; ++c) {
        int row = base + c * 16 + col;
        if (row >= n) row = n - 1;
        size_t roff = (size_t)row * DIN + quad * 8;
#pragma unroll
        for (int kt = 0; kt < KT; ++kt) {
            fh[c][kt] = *(const short8*)(Fh + roff + kt * 32);
            fl[c][kt] = *(const short8*)(Fl + roff + kt * 32);
        }
    }
#pragma unroll
    for (int nt = 0; nt < NT; ++nt) {
#pragma unroll
        for (int kt = 0; kt < KT; ++kt) {
            const ushort_t* p = Wp + ((size_t)((kt * NT + nt) << 6) + lane) * 8;
            short8 bh = *(const short8*)p;
            short8 bl = *(const short8*)(p + (size_t)KT * NT * 512);
#pragma unroll
            for (int c = 0; c < M2; ++c) {
                acc[c][nt] = __builtin_amdgcn_mfma_f32_16x16x32_bf16(fh[c][kt], bh, acc[c][nt], 0, 0, 0);
                acc[c][nt] = __builtin_amdgcn_mfma_f32_16x16x32_bf16(fl[c][kt], bh, acc[c][nt], 0, 0, 0);
                acc[c][nt] = __builtin_amdgcn_mfma_f32_16x16x32_bf16(fh[c][kt], bl, acc[c][nt], 0, 0, 0);
            }
        }
    }
}

template <int DIN, int DOUT, bool HAS_R, bool RELU, bool OUT_SPLIT>
__global__ __launch_bounds__(256)
void k_mfma_dense(const ushort_t* __restrict__ Ah, const ushort_t* __restrict__ Al,
                  const ushort_t* __restrict__ Xh, const ushort_t* __restrict__ Xl,
                  const ushort_t* __restrict__ Wlp, const ushort_t* __restrict__ Wrp,
                  const float* __restrict__ bias,
                  float* __restrict__ outF, ushort_t* __restrict__ Oh,
                  ushort_t* __restrict__ Ol, int n) {
    constexpr int NT = DOUT / 16, M2 = 1;   // 16 rows/wave -> 2x waves vs M2=2
    int wave = (blockIdx.x * blockDim.x + threadIdx.x) >> 6;
    int lane = threadIdx.x & 63;
    int base = wave * (M2 * 16);
    if (base >= n) return;
    int col = lane & 15, quad = lane >> 4;

    f32x4 acc[M2][NT];
#pragma unroll
    for (int nt = 0; nt < NT; ++nt) {
        float bv = bias[nt * 16 + col];
#pragma unroll
        for (int c = 0; c < M2; ++c) acc[c][nt] = (f32x4){bv, bv, bv, bv};
    }

    mfma_pass<DIN, DOUT, M2>(Ah, Al, Wlp, acc, base, n, lane);
    if (HAS_R) mfma_pass<DIN, DOUT, M2>(Xh, Xl, Wrp, acc, base, n, lane);

#pragma unroll
    for (int c = 0; c < M2; ++c) {
        int rowb = base + c * 16 + quad * 4;
#pragma unroll
        for (int nt = 0; nt < NT; ++nt) {
            int cix = nt * 16 + col;
#pragma unroll
            for (int r = 0; r < 4; ++r) {
                int row = rowb + r;
                if (row < n) {
                    float v = acc[c][nt][r];
                    if (RELU) v = fmaxf(v, 0.f);
                    if (OUT_SPLIT) {
                        ushort_t h = bf16_rne(v);
                        Oh[(size_t)row * DOUT + cix] = h;
                        Ol[(size_t)row * DOUT + cix] = bf16_rne(v - bf16_to_f(h));
                    } else {
                        outF[(size_t)row * DOUT + cix] = v;
                    }
                }
            }
        }
    }
}

// ---------------- launch ----------------

static inline size_t align256(size_t x) { return (x + 255) & ~(size_t)255; }

extern "C" void kernel_launch(void* const* d_in, const int* in_sizes, int n_in,
                              void* d_out, int out_size, void* d_ws, size_t ws_size,
                              hipStream_t stream) {
    const float* x   = (const float*)d_in[0];
    const int*   ei  = (const int*)d_in[1];
    const float* Wl1 = (const float*)d_in[2];
    const float* bl1 = (const float*)d_in[3];
    const float* Wr1 = (const float*)d_in[4];
    const float* Wl2 = (const float*)d_in[5];
    const float* bl2 = (const float*)d_in[6];
    const float* Wr2 = (const float*)d_in[7];
    const float* Wo  = (const float*)d_in[8];
    const float* bo  = (const float*)d_in[9];

    const int N = in_sizes[0] / 64;   // 50000
    const int E = in_sizes[1] / 2;    // 1600000
    const int* src = ei;
    const int* dst = ei + E;
    const int nbk = (N + BKT_NODES - 1) >> BKT_SHIFT;   // 391 buckets

    // workspace carve
    char* ws = (char*)d_ws;
    int* off = (int*)ws;            ws += align256((size_t)(N + 1) * 4);
    int* bcnt = (int*)ws;           ws += align256((size_t)nbk * 4);
    int* boff = (int*)ws;           ws += align256((size_t)nbk * 4);
    uint_t* pairs = (uint_t*)ws;    ws += align256((size_t)nbk * BKT_CAP * 4);
    ushort_t* col = (ushort_t*)ws;  ws += align256((size_t)E * 2);
    ushort_t* xh  = (ushort_t*)ws;  ws += align256((size_t)N * 64 * 2);
    ushort_t* xl  = (ushort_t*)ws;  ws += align256((size_t)N * 64 * 2);
    ushort_t* a1h = (ushort_t*)ws;  ws += align256((size_t)N * 64 * 2);
    ushort_t* a1l = (ushort_t*)ws;  ws += align256((size_t)N * 64 * 2);
    ushort_t* h1h = (ushort_t*)ws;  ws += align256((size_t)N * 128 * 2);
    ushort_t* h1l = (ushort_t*)ws;  ws += align256((size_t)N * 128 * 2);
    ushort_t* h2h = (ushort_t*)ws;  ws += align256((size_t)N * 128 * 2);
    ushort_t* h2l = (ushort_t*)ws;  ws += align256((size_t)N * 128 * 2);
    ushort_t* Wl1p = (ushort_t*)ws; ws += align256((size_t)2 * 64 * 128 * 2);
    ushort_t* Wr1p = (ushort_t*)ws; ws += align256((size_t)2 * 64 * 128 * 2);
    ushort_t* Wl2p = (ushort_t*)ws; ws += align256((size_t)2 * 128 * 128 * 2);
    ushort_t* Wr2p = (ushort_t*)ws; ws += align256((size_t)2 * 128 * 128 * 2);
    ushort_t* Wop  = (ushort_t*)ws; ws += align256((size_t)2 * 128 * 64 * 2);
    // a2 aliases dead x/a1 split buffers (consumed by dense1 before agg2)
    ushort_t* a2h = xh;
    ushort_t* a2l = a1h;

    // 1. CSR build (bucketed; convoy-ordered adjacency)
    hipMemsetAsync(bcnt, 0, (size_t)nbk * 4, stream);
    int bbl = (E + EPB - 1) / EPB;
    k_bucket<<<bbl, 1024, 0, stream>>>(src, dst, pairs, bcnt, E, nbk);
    k_bscan<<<1, 512, 0, stream>>>(bcnt, boff, nbk);
    k_csr<<<nbk, 512, 0, stream>>>(pairs, bcnt, boff, off, col, N);

    // 2. split + fused weight packing (independent of CSR)
    k_split<<<(N * 64 + 255) / 256, 256, 0, stream>>>(x, xh, xl, N * 64);
    WPack wp;
    wp.srcp[0] = Wl1; wp.dstp[0] = Wl1p; wp.K[0] = 64;  wp.N[0] = 128;
    wp.srcp[1] = Wr1; wp.dstp[1] = Wr1p; wp.K[1] = 64;  wp.N[1] = 128;
    wp.srcp[2] = Wl2; wp.dstp[2] = Wl2p; wp.K[2] = 128; wp.N[2] = 128;
    wp.srcp[3] = Wr2; wp.dstp[3] = Wr2p; wp.K[3] = 128; wp.N[3] = 128;
    wp.srcp[4] = Wo;  wp.dstp[4] = Wop;  wp.K[4] = 128; wp.N[4] = 64;
    int acc_el = 0;
    for (int m = 0; m < 5; ++m) {
        wp.beg[m] = acc_el; acc_el += wp.K[m] * wp.N[m]; wp.end[m] = acc_el;
    }
    k_pack_all<<<(acc_el + 255) / 256, 256, 0, stream>>>(wp, acc_el);

    // 3. layer 1 (agg gathers bf16-hi x)
    int aggbl = (N * 64 + 255) / 256;            // one wave per node
    k_agg<64><<<aggbl, 256, 0, stream>>>(xh, off, col, a1h, a1l, N);
    int dbl = ((N + 15) / 16 + 3) / 4;           // 16 nodes/wave, 4 waves/block
    k_mfma_dense<64, 128, true, true, true><<<dbl, 256, 0, stream>>>(
        a1h, a1l, xh, xl, Wl1p, Wr1p, bl1, nullptr, h1h, h1l, N);

    // 4. layer 2
    k_agg<128><<<aggbl, 256, 0, stream>>>(h1h, off, col, a2h, a2l, N);
    k_mfma_dense<128, 128, true, true, true><<<dbl, 256, 0, stream>>>(
        a2h, a2l, h1h, h1l, Wl2p, Wr2p, bl2, nullptr, h2h, h2l, N);

    // 5. output layer
    k_mfma_dense<128, 64, false, false, false><<<dbl, 256, 0, stream>>>(
        h2h, h2l, nullptr, nullptr, Wop, nullptr, bo, (float*)d_out, nullptr, nullptr, N);
}

// Round 7
// 243.607 us; speedup vs baseline: 1.1224x; 1.1224x over previous
//
#include <hip/hip_runtime.h>

// GraphSAGE encoder on MI355X.
// 8-dispatch pipeline: memset, bucket, csr(self-scan), prep(split+pack),
// agg64, dense1, agg128, dense2+out(fused).
// Aggregation is at its request-rate floor (~29 L2 lines/cyc vs ~32 ceiling).

typedef unsigned short ushort_t;
typedef unsigned int uint_t;
typedef __attribute__((ext_vector_type(8))) short short8;
typedef __attribute__((ext_vector_type(8))) ushort_t ushort8;
typedef __attribute__((ext_vector_type(4))) float f32x4;

#define BKT_SHIFT 7            // 128 nodes per bucket
#define BKT_NODES 128
#define BKT_CAP   5120         // mean 4092 + 16 sigma headroom
#define EPB       4096         // edges per block in bucket-scatter

// ---------------- bf16 helpers ----------------

__device__ inline ushort_t bf16_rne(float v) {
    uint_t u = __float_as_uint(v);
    u += 0x7fffu + ((u >> 16) & 1u);
    return (ushort_t)(u >> 16);
}
__device__ inline float bf16_to_f(ushort_t h) {
    return __uint_as_float((uint_t)h << 16);
}

// ---------------- CSR build ----------------
// phase 1: bucket edges by dst>>7. 1024 threads/block, 4 lane-interleaved
// sub-histograms, one int4 edge load reused in both passes.

__global__ __launch_bounds__(1024) void k_bucket(const int* __restrict__ src,
                                                 const int* __restrict__ dst,
                                                 uint_t* __restrict__ pairs,
                                                 int* __restrict__ bcnt,
                                                 int E, int nbk) {
    __shared__ int h[4][512];
    int tid = threadIdx.x;
    int sub = tid & 3;
    for (int i = tid; i < 4 * 512; i += 1024) ((int*)h)[i] = 0;
    __syncthreads();

    int e = blockIdx.x * EPB + tid * 4;
    bool full = (e + 4 <= E);
    int4 d4 = {0, 0, 0, 0}, s4 = {0, 0, 0, 0};
    if (full) {
        d4 = *(const int4*)(dst + e);
        s4 = *(const int4*)(src + e);
        atomicAdd(&h[sub][d4.x >> BKT_SHIFT], 1);
        atomicAdd(&h[sub][d4.y >> BKT_SHIFT], 1);
        atomicAdd(&h[sub][d4.z >> BKT_SHIFT], 1);
        atomicAdd(&h[sub][d4.w >> BKT_SHIFT], 1);
    } else {
        for (int t = e; t < E && t < e + 4; ++t)
            atomicAdd(&h[sub][dst[t] >> BKT_SHIFT], 1);
    }
    __syncthreads();
    for (int i = tid; i < nbk; i += 1024) {
        int c0 = h[0][i], c1 = h[1][i], c2 = h[2][i], c3 = h[3][i];
        int c = c0 + c1 + c2 + c3;
        int bs = c ? atomicAdd(&bcnt[i], c) : 0;
        h[0][i] = bs; h[1][i] = bs + c0; h[2][i] = bs + c0 + c1;
        h[3][i] = bs + c0 + c1 + c2;
    }
    __syncthreads();
    if (full) {
        int dd[4] = {d4.x, d4.y, d4.z, d4.w};
        int ss[4] = {s4.x, s4.y, s4.z, s4.w};
#pragma unroll
        for (int t = 0; t < 4; ++t) {
            int b = dd[t] >> BKT_SHIFT;
            int r = atomicAdd(&h[sub][b], 1);
            pairs[(size_t)b * BKT_CAP + r] =
                (uint_t)(ss[t] & 0xFFFF) | ((uint_t)(dd[t] & (BKT_NODES - 1)) << 16);
        }
    } else {
        for (int t = e; t < E && t < e + 4; ++t) {
            int d = dst[t];
            int b = d >> BKT_SHIFT;
            int r = atomicAdd(&h[sub][b], 1);
            pairs[(size_t)b * BKT_CAP + r] =
                (uint_t)(src[t] & 0xFFFF) | ((uint_t)(d & (BKT_NODES - 1)) << 16);
        }
    }
}

// phase 2 (fused): per-bucket self-scan of bucket offsets (bcnt is L2-hot,
// 391 ints) + local histogram + 128-scan + off write + fine scatter.
__global__ __launch_bounds__(512) void k_csr(const uint_t* __restrict__ pairs,
                                             const int* __restrict__ bcnt,
                                             int* __restrict__ off,
                                             ushort_t* __restrict__ col, int n) {
    __shared__ int hist[BKT_NODES];
    __shared__ int s[BKT_NODES];
    __shared__ int cur[BKT_NODES];
    __shared__ int bofs_s;
    int b = blockIdx.x, tid = threadIdx.x;
    // wave 0: exclusive prefix of bcnt over buckets [0, b)
    if (tid < 64) {
        int p = 0;
        for (int i = tid; i < b; i += 64) p += bcnt[i];
#pragma unroll
        for (int m = 1; m < 64; m <<= 1) p += __shfl_xor(p, m);
        if (tid == 0) bofs_s = p;
    }
    if (tid < BKT_NODES) hist[tid] = 0;
    __syncthreads();
    int bofs = bofs_s;
    int cnt = bcnt[b];
    const uint_t* p = pairs + (size_t)b * BKT_CAP;
    for (int i = tid; i < cnt; i += 512) atomicAdd(&hist[(p[i] >> 16) & 127], 1);
    __syncthreads();
    int v = (tid < BKT_NODES) ? hist[tid] : 0;
    if (tid < BKT_NODES) s[tid] = v;
    __syncthreads();
    for (int ofs = 1; ofs < BKT_NODES; ofs <<= 1) {
        int t = (tid >= ofs && tid < BKT_NODES) ? s[tid - ofs] : 0;
        __syncthreads();
        if (tid < BKT_NODES) s[tid] += t;
        __syncthreads();
    }
    if (tid < BKT_NODES) {
        int excl = bofs + s[tid] - v;
        int node = b * BKT_NODES + tid;
        if (node <= n) off[node] = excl;   // node==n lands on E (zero tail deg)
        cur[tid] = excl;
    }
    __syncthreads();
    for (int i = tid; i < cnt; i += 512) {
        uint_t pk = p[i];
        int pos = atomicAdd(&cur[(pk >> 16) & 127], 1);
        col[pos] = (ushort_t)(pk & 0xFFFF);
    }
}

// ---------------- fused input split + weight pack ----------------

struct WPack {
    const float* srcp[5];
    ushort_t* dstp[5];
    int K[5], N[5], beg[5], end[5];
};

// t < NS: elementwise fp32 x -> (hi,lo) bf16.  t >= NS: pack W (K x N
// row-major fp32) into MFMA B-frag order, hi then lo:
// dst[hl][kt][nt][lane][j], lane=(k/8%4)*16+(n%16), j=k%8.
__global__ void k_prep(const float* __restrict__ x, ushort_t* __restrict__ xh,
                       ushort_t* __restrict__ xl, int NS, WPack wp, int total) {
    int t = blockIdx.x * blockDim.x + threadIdx.x;
    if (t < NS) {
        float v = x[t];
        ushort_t h = bf16_rne(v);
        xh[t] = h;
        xl[t] = bf16_rne(v - bf16_to_f(h));
        return;
    }
    t -= NS;
    if (t >= total) return;
#pragma unroll
    for (int m = 0; m < 5; ++m) {
        if (t >= wp.beg[m] && t < wp.end[m]) {
            int i = t - wp.beg[m];
            int K = wp.K[m], N = wp.N[m];
            int k = i / N, nn = i % N;
            int KT = K >> 5, NT = N >> 4;
            int kt = k >> 5, bq = (k >> 3) & 3, j = k & 7;
            int nt = nn >> 4, lane = (bq << 4) | (nn & 15);
            int base = (((kt * NT + nt) << 6) + lane) * 8 + j;
            int halfsz = KT * NT * 512;
            float v = wp.srcp[m][i];
            ushort_t h = bf16_rne(v);
            wp.dstp[m][base] = h;
            wp.dstp[m][halfsz + base] = bf16_rne(v - bf16_to_f(h));
        }
    }
}

// ---------------- mean aggregation ----------------
// One wave per node. 16B/lane packed-bf16 gathers, LPR lanes/row, EPI edges
// per instruction, DEEP independent gathers in flight. shfl_xor butterfly.

__device__ inline void accum2(float2 (&a)[4], uint4 q) {
    const uint_t* u = (const uint_t*)&q;
#pragma unroll
    for (int i = 0; i < 4; ++i) {
        a[i].x += __uint_as_float(u[i] << 16);
        a[i].y += __uint_as_float(u[i] & 0xffff0000u);
    }
}
__device__ inline void accum2m(float2 (&a)[4], uint4 q, float m) {
    const uint_t* u = (const uint_t*)&q;
#pragma unroll
    for (int i = 0; i < 4; ++i) {
        a[i].x = fmaf(m, __uint_as_float(u[i] << 16), a[i].x);
        a[i].y = fmaf(m, __uint_as_float(u[i] & 0xffff0000u), a[i].y);
    }
}

template <int DIN>
__global__ __launch_bounds__(256) void k_agg(const ushort_t* __restrict__ fh,
                                             const int* __restrict__ off,
                                             const ushort_t* __restrict__ col,
                                             ushort_t* __restrict__ ah,
                                             ushort_t* __restrict__ al, int n) {
    constexpr int LPR = DIN / 8;       // lanes per row: 8 (D64) / 16 (D128)
    constexpr int EPI = 64 / LPR;      // edges per instruction: 8 / 4
    constexpr int DEEP = (DIN == 128) ? 8 : 4;   // gathers in flight
    int wave = (int)((blockIdx.x * (unsigned)blockDim.x + threadIdx.x) >> 6);
    int lane = threadIdx.x & 63;
    if (wave >= n) return;
    int li = lane & (LPR - 1);         // column slice
    int sub = lane / LPR;              // edge slot
    int s0 = off[wave], s1 = off[wave + 1];
    float2 a2[4] = {{0.f, 0.f}, {0.f, 0.f}, {0.f, 0.f}, {0.f, 0.f}};
    const ushort_t* __restrict__ fbase = fh + li * 8;

    int e = s0;
    for (; e + DEEP * EPI <= s1; e += DEEP * EPI) {
        int c[DEEP];
        uint4 q[DEEP];
#pragma unroll
        for (int j = 0; j < DEEP; ++j) c[j] = col[e + j * EPI + sub];
#pragma unroll
        for (int j = 0; j < DEEP; ++j) q[j] = *(const uint4*)(fbase + (size_t)c[j] * DIN);
#pragma unroll
        for (int j = 0; j < DEEP; ++j) accum2(a2, q[j]);
    }
    for (; e < s1; e += 4 * EPI) {
        int last = s1 - 1;
        int i0 = e + sub, i1 = i0 + EPI, i2 = i1 + EPI, i3 = i2 + EPI;
        float m0 = (i0 < s1) ? 1.f : 0.f;
        float m1 = (i1 < s1) ? 1.f : 0.f;
        float m2 = (i2 < s1) ? 1.f : 0.f;
        float m3 = (i3 < s1) ? 1.f : 0.f;
        int c0 = col[min(i0, last)];
        int c1 = col[min(i1, last)];
        int c2 = col[min(i2, last)];
        int c3 = col[min(i3, last)];
        uint4 q0 = *(const uint4*)(fbase + (size_t)c0 * DIN);
        uint4 q1 = *(const uint4*)(fbase + (size_t)c1 * DIN);
        uint4 q2 = *(const uint4*)(fbase + (size_t)c2 * DIN);
        uint4 q3 = *(const uint4*)(fbase + (size_t)c3 * DIN);
        accum2m(a2, q0, m0); accum2m(a2, q1, m1);
        accum2m(a2, q2, m2); accum2m(a2, q3, m3);
    }
#pragma unroll
    for (int m = LPR; m < 64; m <<= 1) {
#pragma unroll
        for (int j = 0; j < 4; ++j) {
            a2[j].x += __shfl_xor(a2[j].x, m);
            a2[j].y += __shfl_xor(a2[j].y, m);
        }
    }
    if (sub == 0) {
        float inv = 1.f / fmaxf((float)(s1 - s0), 1.f);
        ushort8 vh, vl;
#pragma unroll
        for (int j = 0; j < 4; ++j) {
            float mx = a2[j].x * inv;
            float my = a2[j].y * inv;
            ushort_t hx = bf16_rne(mx), hy = bf16_rne(my);
            vh[2 * j] = hx;     vl[2 * j] = bf16_rne(mx - bf16_to_f(hx));
            vh[2 * j + 1] = hy; vl[2 * j + 1] = bf16_rne(my - bf16_to_f(hy));
        }
        *(ushort8*)(ah + (size_t)wave * DIN + li * 8) = vh;
        *(ushort8*)(al + (size_t)wave * DIN + li * 8) = vl;
    }
}

// ---------------- MFMA dense ----------------
// acc += (Fh+Fl) @ (Wh+Wl) via 3 MFMA products per tile.
// A-frag: 16B contiguous loads from row-major bf16. B-frag: prepacked,
// lane-indexed 16B loads (L1-hot). C/D: col=lane&15, row=(lane>>4)*4+reg.

template <int DIN, int DOUT, int M2>
__device__ inline void mfma_pass(const ushort_t* __restrict__ Fh,
                                 const ushort_t* __restrict__ Fl,
                                 const ushort_t* __restrict__ Wp,
                                 f32x4 (&acc)[M2][DOUT / 16],
                                 int base, int n, int lane) {
    constexpr int KT = DIN / 32, NT = DOUT / 16;
    int col = lane & 15, quad = lane >> 4;
    short8 fh[M2][KT], fl[M2][KT];
#pragma unroll
    for (int c = 0; c < M2; ++c) {
        int row = base + c * 16 + col;
        if (row >= n) row = n - 1;
        size_t roff = (size_t)row * DIN + quad * 8;
#pragma unroll
        for (int kt = 0; kt < KT; ++kt) {
            fh[c][kt] = *(const short8*)(Fh + roff + kt * 32);
            fl[c][kt] = *(const short8*)(Fl + roff + kt * 32);
        }
    }
#pragma unroll
    for (int nt = 0; nt < NT; ++nt) {
#pragma unroll
        for (int kt = 0; kt < KT; ++kt) {
            const ushort_t* p = Wp + ((size_t)((kt * NT + nt) << 6) + lane) * 8;
            short8 bh = *(const short8*)p;
            short8 bl = *(const short8*)(p + (size_t)KT * NT * 512);
#pragma unroll
            for (int c = 0; c < M2; ++c) {
                acc[c][nt] = __builtin_amdgcn_mfma_f32_16x16x32_bf16(fh[c][kt], bh, acc[c][nt], 0, 0, 0);
                acc[c][nt] = __builtin_amdgcn_mfma_f32_16x16x32_bf16(fl[c][kt], bh, acc[c][nt], 0, 0, 0);
                acc[c][nt] = __builtin_amdgcn_mfma_f32_16x16x32_bf16(fh[c][kt], bl, acc[c][nt], 0, 0, 0);
            }
        }
    }
}

// layer 1 dense: h1 = relu(a1@Wl1 + x@Wr1 + b1), split-bf16 out. M2=2.
__global__ __launch_bounds__(256)
void k_dense1(const ushort_t* __restrict__ Ah, const ushort_t* __restrict__ Al,
              const ushort_t* __restrict__ Xh, const ushort_t* __restrict__ Xl,
              const ushort_t* __restrict__ Wlp, const ushort_t* __restrict__ Wrp,
              const float* __restrict__ bias,
              ushort_t* __restrict__ Oh, ushort_t* __restrict__ Ol, int n) {
    constexpr int DIN = 64, DOUT = 128, NT = DOUT / 16, M2 = 2;
    int wave = (blockIdx.x * blockDim.x + threadIdx.x) >> 6;
    int lane = threadIdx.x & 63;
    int base = wave * (M2 * 16);
    if (base >= n) return;
    int col = lane & 15, quad = lane >> 4;

    f32x4 acc[M2][NT];
#pragma unroll
    for (int nt = 0; nt < NT; ++nt) {
        float bv = bias[nt * 16 + col];
#pragma unroll
        for (int c = 0; c < M2; ++c) acc[c][nt] = (f32x4){bv, bv, bv, bv};
    }
    mfma_pass<DIN, DOUT, M2>(Ah, Al, Wlp, acc, base, n, lane);
    mfma_pass<DIN, DOUT, M2>(Xh, Xl, Wrp, acc, base, n, lane);

#pragma unroll
    for (int c = 0; c < M2; ++c) {
        int rowb = base + c * 16 + quad * 4;
#pragma unroll
        for (int nt = 0; nt < NT; ++nt) {
            int cix = nt * 16 + col;
#pragma unroll
            for (int r = 0; r < 4; ++r) {
                int row = rowb + r;
                if (row < n) {
                    float v = fmaxf(acc[c][nt][r], 0.f);
                    ushort_t h = bf16_rne(v);
                    Oh[(size_t)row * DOUT + cix] = h;
                    Ol[(size_t)row * DOUT + cix] = bf16_rne(v - bf16_to_f(h));
                }
            }
        }
    }
}

// fused layer 2 + output: out = (relu(a2@Wl2 + h1@Wr2 + b2)) @ Wo + bo.
// Stage 1 (M2=1, 16 rows/wave) -> relu + split into per-wave LDS (row stride
// 136 ushorts: 2-way bank conflict = free) -> stage 2 MFMA from LDS A-frags.
// h2 never touches HBM.
#define LROW 136
__global__ __launch_bounds__(256)
void k_dense23(const ushort_t* __restrict__ Ah, const ushort_t* __restrict__ Al,
               const ushort_t* __restrict__ Xh, const ushort_t* __restrict__ Xl,
               const ushort_t* __restrict__ Wlp, const ushort_t* __restrict__ Wrp,
               const float* __restrict__ b2, const ushort_t* __restrict__ Wop,
               const float* __restrict__ bo, float* __restrict__ out, int n) {
    constexpr int DIN = 128, DOUT = 128, NT = DOUT / 16;
    __shared__ ushort_t lds[4][2][16 * LROW];   // [wave][hi/lo][row][col]
    int waveid = threadIdx.x >> 6;
    int lane = threadIdx.x & 63;
    int wave = (blockIdx.x * blockDim.x + threadIdx.x) >> 6;
    int nw = (n + 15) / 16;
    if (wave >= nw) wave = nw - 1;     // dup-compute tail; no early return (barrier)
    int base = wave * 16;
    int col = lane & 15, quad = lane >> 4;

    // ---- stage 1: h2 tile ----
    f32x4 acc[1][NT];
#pragma unroll
    for (int nt = 0; nt < NT; ++nt) {
        float bv = b2[nt * 16 + col];
        acc[0][nt] = (f32x4){bv, bv, bv, bv};
    }
    mfma_pass<DIN, DOUT, 1>(Ah, Al, Wlp, acc, base, n, lane);
    mfma_pass<DIN, DOUT, 1>(Xh, Xl, Wrp, acc, base, n, lane);

    ushort_t* Lh = &lds[waveid][0][0];
    ushort_t* Ll = &lds[waveid][1][0];
#pragma unroll
    for (int nt = 0; nt < NT; ++nt) {
        int cix = nt * 16 + col;
#pragma unroll
        for (int r = 0; r < 4; ++r) {
            int row = quad * 4 + r;
            float v = fmaxf(acc[0][nt][r], 0.f);
            ushort_t h = bf16_rne(v);
            Lh[row * LROW + cix] = h;
            Ll[row * LROW + cix] = bf16_rne(v - bf16_to_f(h));
        }
    }
    __syncthreads();

    // ---- stage 2: out tile = h2 @ Wo + bo (K=128, DOUT2=64) ----
    constexpr int KT2 = 4, NT2 = 4;
    short8 ah[KT2], al[KT2];
    int arow = lane & 15;
#pragma unroll
    for (int kt = 0; kt < KT2; ++kt) {
        ah[kt] = *(const short8*)(Lh + arow * LROW + kt * 32 + quad * 8);
        al[kt] = *(const short8*)(Ll + arow * LROW + kt * 32 + quad * 8);
    }
    f32x4 acc2[NT2];
#pragma unroll
    for (int nt = 0; nt < NT2; ++nt) {
        float bv = bo[nt * 16 + col];
        acc2[nt] = (f32x4){bv, bv, bv, bv};
    }
#pragma unroll
    for (int nt = 0; nt < NT2; ++nt) {
#pragma unroll
        for (int kt = 0; kt < KT2; ++kt) {
            const ushort_t* p = Wop + ((size_t)((kt * NT2 + nt) << 6) + lane) * 8;
            short8 bh = *(const short8*)p;
            short8 bl = *(const short8*)(p + (size_t)KT2 * NT2 * 512);
            acc2[nt] = __builtin_amdgcn_mfma_f32_16x16x32_bf16(ah[kt], bh, acc2[nt], 0, 0, 0);
            acc2[nt] = __builtin_amdgcn_mfma_f32_16x16x32_bf16(al[kt], bh, acc2[nt], 0, 0, 0);
            acc2[nt] = __builtin_amdgcn_mfma_f32_16x16x32_bf16(ah[kt], bl, acc2[nt], 0, 0, 0);
        }
    }
    int rowb = base + quad * 4;
#pragma unroll
    for (int nt = 0; nt < NT2; ++nt) {
        int cix = nt * 16 + col;
#pragma unroll
        for (int r = 0; r < 4; ++r) {
            int row = rowb + r;
            if (row < n) out[(size_t)row * 64 + cix] = acc2[nt][r];
        }
    }
}

// ---------------- launch ----------------

static inline size_t align256(size_t x) { return (x + 255) & ~(size_t)255; }

extern "C" void kernel_launch(void* const* d_in, const int* in_sizes, int n_in,
                              void* d_out, int out_size, void* d_ws, size_t ws_size,
                              hipStream_t stream) {
    const float* x   = (const float*)d_in[0];
    const int*   ei  = (const int*)d_in[1];
    const float* Wl1 = (const float*)d_in[2];
    const float* bl1 = (const float*)d_in[3];
    const float* Wr1 = (const float*)d_in[4];
    const float* Wl2 = (const float*)d_in[5];
    const float* bl2 = (const float*)d_in[6];
    const float* Wr2 = (const float*)d_in[7];
    const float* Wo  = (const float*)d_in[8];
    const float* bo  = (const float*)d_in[9];

    const int N = in_sizes[0] / 64;   // 50000
    const int E = in_sizes[1] / 2;    // 1600000
    const int* src = ei;
    const int* dst = ei + E;
    const int nbk = (N + BKT_NODES - 1) >> BKT_SHIFT;   // 391 buckets

    // workspace carve
    char* ws = (char*)d_ws;
    int* off = (int*)ws;            ws += align256((size_t)(N + 1) * 4);
    int* bcnt = (int*)ws;           ws += align256((size_t)nbk * 4);
    uint_t* pairs = (uint_t*)ws;    ws += align256((size_t)nbk * BKT_CAP * 4);
    ushort_t* col = (ushort_t*)ws;  ws += align256((size_t)E * 2);
    ushort_t* xh  = (ushort_t*)ws;  ws += align256((size_t)N * 64 * 2);
    ushort_t* xl  = (ushort_t*)ws;  ws += align256((size_t)N * 64 * 2);
    ushort_t* a1h = (ushort_t*)ws;  ws += align256((size_t)N * 64 * 2);
    ushort_t* a1l = (ushort_t*)ws;  ws += align256((size_t)N * 64 * 2);
    ushort_t* h1h = (ushort_t*)ws;  ws += align256((size_t)N * 128 * 2);
    ushort_t* h1l = (ushort_t*)ws;  ws += align256((size_t)N * 128 * 2);
    ushort_t* Wl1p = (ushort_t*)ws; ws += align256((size_t)2 * 64 * 128 * 2);
    ushort_t* Wr1p = (ushort_t*)ws; ws += align256((size_t)2 * 64 * 128 * 2);
    ushort_t* Wl2p = (ushort_t*)ws; ws += align256((size_t)2 * 128 * 128 * 2);
    ushort_t* Wr2p = (ushort_t*)ws; ws += align256((size_t)2 * 128 * 128 * 2);
    ushort_t* Wop  = (ushort_t*)ws; ws += align256((size_t)2 * 128 * 64 * 2);
    // a2 aliases dead x/a1 split buffers (consumed by dense1 before agg2)
    ushort_t* a2h = xh;
    ushort_t* a2l = a1h;

    // 1. CSR build
    hipMemsetAsync(bcnt, 0, (size_t)nbk * 4, stream);
    int bbl = (E + EPB - 1) / EPB;
    k_bucket<<<bbl, 1024, 0, stream>>>(src, dst, pairs, bcnt, E, nbk);
    k_csr<<<nbk, 512, 0, stream>>>(pairs, bcnt, off, col, N);

    // 2. fused split + weight packing
    WPack wp;
    wp.srcp[0] = Wl1; wp.dstp[0] = Wl1p; wp.K[0] = 64;  wp.N[0] = 128;
    wp.srcp[1] = Wr1; wp.dstp[1] = Wr1p; wp.K[1] = 64;  wp.N[1] = 128;
    wp.srcp[2] = Wl2; wp.dstp[2] = Wl2p; wp.K[2] = 128; wp.N[2] = 128;
    wp.srcp[3] = Wr2; wp.dstp[3] = Wr2p; wp.K[3] = 128; wp.N[3] = 128;
    wp.srcp[4] = Wo;  wp.dstp[4] = Wop;  wp.K[4] = 128; wp.N[4] = 64;
    int acc_el = 0;
    for (int m = 0; m < 5; ++m) {
        wp.beg[m] = acc_el; acc_el += wp.K[m] * wp.N[m]; wp.end[m] = acc_el;
    }
    int NS = N * 64;
    k_prep<<<(NS + acc_el + 255) / 256, 256, 0, stream>>>(x, xh, xl, NS, wp, acc_el);

    // 3. layer 1
    int aggbl = (N * 64 + 255) / 256;            // one wave per node
    k_agg<64><<<aggbl, 256, 0, stream>>>(xh, off, col, a1h, a1l, N);
    int dbl1 = ((N + 31) / 32 + 3) / 4;          // 32 rows/wave (M2=2)
    k_dense1<<<dbl1, 256, 0, stream>>>(a1h, a1l, xh, xl, Wl1p, Wr1p, bl1, h1h, h1l, N);

    // 4. layer 2 + output (fused)
    k_agg<128><<<aggbl, 256, 0, stream>>>(h1h, off, col, a2h, a2l, N);
    int dbl2 = ((N + 15) / 16 + 3) / 4;          // 16 rows/wave (M2=1)
    k_dense23<<<dbl2, 256, 0, stream>>>(a2h, a2l, h1h, h1l, Wl2p, Wr2p, bl2,
                                        Wop, bo, (float*)d_out, N);
}

// Round 8
// 237.620 us; speedup vs baseline: 1.1506x; 1.0252x over previous
//
#include <hip/hip_runtime.h>

// GraphSAGE encoder on MI355X — 5-dispatch pipeline:
//   k_prep (bcnt zero + x split + weight pack)
//   k_bucket (edges -> 391 dst-buckets, LDS histograms)
//   k_csr (per-bucket scan + fine scatter -> CSR)
//   k_layer1 (agg64 + dense1 fused; a1 lives in LDS only)
//   k_layer2 (agg128 + dense2 + out fused; a2,h2 live in LDS only)
// Aggregation gathers are at the L2-request-rate floor (~29 lines/cyc).
// Dense uses split-bf16 MFMA: A@B ~= Ah@Bh + Al@Bh + Ah@Bl (fp32-equivalent).

typedef unsigned short ushort_t;
typedef unsigned int uint_t;
typedef __attribute__((ext_vector_type(8))) short short8;
typedef __attribute__((ext_vector_type(8))) ushort_t ushort8;
typedef __attribute__((ext_vector_type(4))) float f32x4;

#define BKT_SHIFT 7            // 128 nodes per bucket
#define BKT_NODES 128
#define BKT_CAP   5120         // mean 4092 + 16 sigma headroom
#define EPB       4096         // edges per block in bucket-scatter

// ---------------- bf16 helpers ----------------

__device__ inline ushort_t bf16_rne(float v) {
    uint_t u = __float_as_uint(v);
    u += 0x7fffu + ((u >> 16) & 1u);
    return (ushort_t)(u >> 16);
}
__device__ inline float bf16_to_f(ushort_t h) {
    return __uint_as_float((uint_t)h << 16);
}

// ---------------- CSR build ----------------

__global__ __launch_bounds__(1024) void k_bucket(const int* __restrict__ src,
                                                 const int* __restrict__ dst,
                                                 uint_t* __restrict__ pairs,
                                                 int* __restrict__ bcnt,
                                                 int E, int nbk) {
    __shared__ int h[4][512];
    int tid = threadIdx.x;
    int sub = tid & 3;
    for (int i = tid; i < 4 * 512; i += 1024) ((int*)h)[i] = 0;
    __syncthreads();

    int e = blockIdx.x * EPB + tid * 4;
    bool full = (e + 4 <= E);
    int4 d4 = {0, 0, 0, 0}, s4 = {0, 0, 0, 0};
    if (full) {
        d4 = *(const int4*)(dst + e);
        s4 = *(const int4*)(src + e);
        atomicAdd(&h[sub][d4.x >> BKT_SHIFT], 1);
        atomicAdd(&h[sub][d4.y >> BKT_SHIFT], 1);
        atomicAdd(&h[sub][d4.z >> BKT_SHIFT], 1);
        atomicAdd(&h[sub][d4.w >> BKT_SHIFT], 1);
    } else {
        for (int t = e; t < E && t < e + 4; ++t)
            atomicAdd(&h[sub][dst[t] >> BKT_SHIFT], 1);
    }
    __syncthreads();
    for (int i = tid; i < nbk; i += 1024) {
        int c0 = h[0][i], c1 = h[1][i], c2 = h[2][i], c3 = h[3][i];
        int c = c0 + c1 + c2 + c3;
        int bs = c ? atomicAdd(&bcnt[i], c) : 0;
        h[0][i] = bs; h[1][i] = bs + c0; h[2][i] = bs + c0 + c1;
        h[3][i] = bs + c0 + c1 + c2;
    }
    __syncthreads();
    if (full) {
        int dd[4] = {d4.x, d4.y, d4.z, d4.w};
        int ss[4] = {s4.x, s4.y, s4.z, s4.w};
#pragma unroll
        for (int t = 0; t < 4; ++t) {
            int b = dd[t] >> BKT_SHIFT;
            int r = atomicAdd(&h[sub][b], 1);
            pairs[(size_t)b * BKT_CAP + r] =
                (uint_t)(ss[t] & 0xFFFF) | ((uint_t)(dd[t] & (BKT_NODES - 1)) << 16);
        }
    } else {
        for (int t = e; t < E && t < e + 4; ++t) {
            int d = dst[t];
            int b = d >> BKT_SHIFT;
            int r = atomicAdd(&h[sub][b], 1);
            pairs[(size_t)b * BKT_CAP + r] =
                (uint_t)(src[t] & 0xFFFF) | ((uint_t)(d & (BKT_NODES - 1)) << 16);
        }
    }
}

__global__ __launch_bounds__(512) void k_csr(const uint_t* __restrict__ pairs,
                                             const int* __restrict__ bcnt,
                                             int* __restrict__ off,
                                             ushort_t* __restrict__ col, int n) {
    __shared__ int hist[BKT_NODES];
    __shared__ int s[BKT_NODES];
    __shared__ int cur[BKT_NODES];
    __shared__ int bofs_s;
    int b = blockIdx.x, tid = threadIdx.x;
    if (tid < 64) {                    // wave 0: prefix of bcnt over [0, b)
        int p = 0;
        for (int i = tid; i < b; i += 64) p += bcnt[i];
#pragma unroll
        for (int m = 1; m < 64; m <<= 1) p += __shfl_xor(p, m);
        if (tid == 0) bofs_s = p;
    }
    if (tid < BKT_NODES) hist[tid] = 0;
    __syncthreads();
    int bofs = bofs_s;
    int cnt = bcnt[b];
    const uint_t* p = pairs + (size_t)b * BKT_CAP;
    for (int i = tid; i < cnt; i += 512) atomicAdd(&hist[(p[i] >> 16) & 127], 1);
    __syncthreads();
    int v = (tid < BKT_NODES) ? hist[tid] : 0;
    if (tid < BKT_NODES) s[tid] = v;
    __syncthreads();
    for (int ofs = 1; ofs < BKT_NODES; ofs <<= 1) {
        int t = (tid >= ofs && tid < BKT_NODES) ? s[tid - ofs] : 0;
        __syncthreads();
        if (tid < BKT_NODES) s[tid] += t;
        __syncthreads();
    }
    if (tid < BKT_NODES) {
        int excl = bofs + s[tid] - v;
        int node = b * BKT_NODES + tid;
        if (node <= n) off[node] = excl;
        cur[tid] = excl;
    }
    __syncthreads();
    for (int i = tid; i < cnt; i += 512) {
        uint_t pk = p[i];
        int pos = atomicAdd(&cur[(pk >> 16) & 127], 1);
        col[pos] = (ushort_t)(pk & 0xFFFF);
    }
}

// ---------------- prep: bcnt zero + x split + weight pack ----------------

struct WPack {
    const float* srcp[5];
    ushort_t* dstp[5];
    int K[5], N[5], beg[5], end[5];
};

__global__ void k_prep(const float* __restrict__ x, ushort_t* __restrict__ xh,
                       ushort_t* __restrict__ xl, int NS, WPack wp, int total,
                       int* __restrict__ bcnt, int nbk) {
    int t = blockIdx.x * blockDim.x + threadIdx.x;
    if (t < nbk) bcnt[t] = 0;
    if (t < NS) {
        float v = x[t];
        ushort_t h = bf16_rne(v);
        xh[t] = h;
        xl[t] = bf16_rne(v - bf16_to_f(h));
        return;
    }
    t -= NS;
    if (t >= total) return;
#pragma unroll
    for (int m = 0; m < 5; ++m) {
        if (t >= wp.beg[m] && t < wp.end[m]) {
            int i = t - wp.beg[m];
            int K = wp.K[m], N = wp.N[m];
            int k = i / N, nn = i % N;
            int KT = K >> 5, NT = N >> 4;
            int kt = k >> 5, bq = (k >> 3) & 3, j = k & 7;
            int nt = nn >> 4, lane = (bq << 4) | (nn & 15);
            int base = (((kt * NT + nt) << 6) + lane) * 8 + j;
            int halfsz = KT * NT * 512;
            float v = wp.srcp[m][i];
            ushort_t h = bf16_rne(v);
            wp.dstp[m][base] = h;
            wp.dstp[m][halfsz + base] = bf16_rne(v - bf16_to_f(h));
        }
    }
}

// ---------------- aggregation inner loop (per node, per wave) ----------------

__device__ inline void accum2(float2 (&a)[4], uint4 q) {
    const uint_t* u = (const uint_t*)&q;
#pragma unroll
    for (int i = 0; i < 4; ++i) {
        a[i].x += __uint_as_float(u[i] << 16);
        a[i].y += __uint_as_float(u[i] & 0xffff0000u);
    }
}
__device__ inline void accum2m(float2 (&a)[4], uint4 q, float m) {
    const uint_t* u = (const uint_t*)&q;
#pragma unroll
    for (int i = 0; i < 4; ++i) {
        a[i].x = fmaf(m, __uint_as_float(u[i] << 16), a[i].x);
        a[i].y = fmaf(m, __uint_as_float(u[i] & 0xffff0000u), a[i].y);
    }
}

template <int DIN>
__device__ inline void agg_node(const ushort_t* __restrict__ fbase,
                                const ushort_t* __restrict__ col,
                                int s0, int s1, int sub, float2 (&a2)[4]) {
    constexpr int LPR = DIN / 8, EPI = 64 / LPR;
    constexpr int DEEP = (DIN == 128) ? 8 : 4;
#pragma unroll
    for (int j = 0; j < 4; ++j) a2[j] = (float2){0.f, 0.f};
    int e = s0;
    for (; e + DEEP * EPI <= s1; e += DEEP * EPI) {
        int c[DEEP];
        uint4 q[DEEP];
#pragma unroll
        for (int j = 0; j < DEEP; ++j) c[j] = col[e + j * EPI + sub];
#pragma unroll
        for (int j = 0; j < DEEP; ++j) q[j] = *(const uint4*)(fbase + (size_t)c[j] * DIN);
#pragma unroll
        for (int j = 0; j < DEEP; ++j) accum2(a2, q[j]);
    }
    for (; e < s1; e += 4 * EPI) {
        int last = s1 - 1;
        int i0 = e + sub, i1 = i0 + EPI, i2 = i1 + EPI, i3 = i2 + EPI;
        float m0 = (i0 < s1) ? 1.f : 0.f;
        float m1 = (i1 < s1) ? 1.f : 0.f;
        float m2 = (i2 < s1) ? 1.f : 0.f;
        float m3 = (i3 < s1) ? 1.f : 0.f;
        int c0 = col[min(i0, last)];
        int c1 = col[min(i1, last)];
        int c2 = col[min(i2, last)];
        int c3 = col[min(i3, last)];
        uint4 q0 = *(const uint4*)(fbase + (size_t)c0 * DIN);
        uint4 q1 = *(const uint4*)(fbase + (size_t)c1 * DIN);
        uint4 q2 = *(const uint4*)(fbase + (size_t)c2 * DIN);
        uint4 q3 = *(const uint4*)(fbase + (size_t)c3 * DIN);
        accum2m(a2, q0, m0); accum2m(a2, q1, m1);
        accum2m(a2, q2, m2); accum2m(a2, q3, m3);
    }
}

__device__ inline f32x4 mfma3(f32x4 acc, short8 ah, short8 al, short8 bh, short8 bl) {
    acc = __builtin_amdgcn_mfma_f32_16x16x32_bf16(ah, bh, acc, 0, 0, 0);
    acc = __builtin_amdgcn_mfma_f32_16x16x32_bf16(al, bh, acc, 0, 0, 0);
    acc = __builtin_amdgcn_mfma_f32_16x16x32_bf16(ah, bl, acc, 0, 0, 0);
    return acc;
}

// ---------------- layer 1 fused: agg64 + dense1 ----------------
// Block = 4 waves = 32 nodes. Phase 1: each wave mean-aggregates 8 nodes into
// LDS (split bf16). Phase 2: each wave computes one 16x64 quadrant of
// h1 = relu(a1@Wl1 + x@Wr1 + b1); a1 A-frags from LDS, x A-frags coalesced.

__global__ __launch_bounds__(256)
void k_layer1(const ushort_t* __restrict__ xh, const ushort_t* __restrict__ xl,
              const int* __restrict__ off, const ushort_t* __restrict__ col,
              const ushort_t* __restrict__ Wlp, const ushort_t* __restrict__ Wrp,
              const float* __restrict__ bias,
              ushort_t* __restrict__ Oh, ushort_t* __restrict__ Ol, int n) {
    constexpr int LPR = 8;
    __shared__ ushort_t Ahs[32][72];   // stride 72: 2-way bank alias (free)
    __shared__ ushort_t Als[32][72];
    int tid = threadIdx.x, waveid = tid >> 6, lane = tid & 63;
    int base = blockIdx.x * 32;
    int li = lane & (LPR - 1);
    int sub = lane / LPR;
    const ushort_t* fbase = xh + li * 8;

    for (int q = 0; q < 8; ++q) {
        int node = base + waveid * 8 + q;
        int nd = node < n ? node : n - 1;
        int s0 = off[nd], s1 = off[nd + 1];
        float2 a2[4];
        agg_node<64>(fbase, col, s0, s1, sub, a2);
#pragma unroll
        for (int m = LPR; m < 64; m <<= 1) {
#pragma unroll
            for (int j = 0; j < 4; ++j) {
                a2[j].x += __shfl_xor(a2[j].x, m);
                a2[j].y += __shfl_xor(a2[j].y, m);
            }
        }
        if (sub == 0) {
            float inv = 1.f / fmaxf((float)(s1 - s0), 1.f);
            ushort8 vh, vl;
#pragma unroll
            for (int j = 0; j < 4; ++j) {
                float mx = a2[j].x * inv, my = a2[j].y * inv;
                ushort_t hx = bf16_rne(mx), hy = bf16_rne(my);
                vh[2 * j] = hx;     vl[2 * j] = bf16_rne(mx - bf16_to_f(hx));
                vh[2 * j + 1] = hy; vl[2 * j + 1] = bf16_rne(my - bf16_to_f(hy));
            }
            *(ushort8*)&Ahs[waveid * 8 + q][li * 8] = vh;
            *(ushort8*)&Als[waveid * 8 + q][li * 8] = vl;
        }
    }
    __syncthreads();

    // dense quadrant: rowt = waveid>>1 (16-row half), colh = waveid&1 (64-col half)
    int rowt = waveid >> 1, colh = waveid & 1;
    int colq = lane & 15, quad = lane >> 4;
    int arow = rowt * 16 + colq;
    short8 fah[2], fal[2], fxh[2], fxl[2];
#pragma unroll
    for (int kt = 0; kt < 2; ++kt) {
        fah[kt] = *(const short8*)&Ahs[arow][kt * 32 + quad * 8];
        fal[kt] = *(const short8*)&Als[arow][kt * 32 + quad * 8];
    }
    int grow = base + arow; if (grow >= n) grow = n - 1;
#pragma unroll
    for (int kt = 0; kt < 2; ++kt) {
        fxh[kt] = *(const short8*)(xh + (size_t)grow * 64 + kt * 32 + quad * 8);
        fxl[kt] = *(const short8*)(xl + (size_t)grow * 64 + kt * 32 + quad * 8);
    }
    f32x4 acc[4];
#pragma unroll
    for (int t = 0; t < 4; ++t) {
        float bv = bias[(colh * 4 + t) * 16 + colq];
        acc[t] = (f32x4){bv, bv, bv, bv};
    }
#pragma unroll
    for (int t = 0; t < 4; ++t) {
        int nt = colh * 4 + t;
#pragma unroll
        for (int kt = 0; kt < 2; ++kt) {
            const ushort_t* pL = Wlp + ((size_t)((kt * 8 + nt) << 6) + lane) * 8;
            acc[t] = mfma3(acc[t], fah[kt], fal[kt],
                           *(const short8*)pL, *(const short8*)(pL + 8192));
            const ushort_t* pR = Wrp + ((size_t)((kt * 8 + nt) << 6) + lane) * 8;
            acc[t] = mfma3(acc[t], fxh[kt], fxl[kt],
                           *(const short8*)pR, *(const short8*)(pR + 8192));
        }
    }
    int rowb = base + rowt * 16 + quad * 4;
#pragma unroll
    for (int t = 0; t < 4; ++t) {
        int cix = colh * 64 + t * 16 + colq;
#pragma unroll
        for (int r = 0; r < 4; ++r) {
            int row = rowb + r;
            if (row < n) {
                float v = fmaxf(acc[t][r], 0.f);
                ushort_t h = bf16_rne(v);
                Oh[(size_t)row * 128 + cix] = h;
                Ol[(size_t)row * 128 + cix] = bf16_rne(v - bf16_to_f(h));
            }
        }
    }
}

// ---------------- layer 2 fused: agg128 + dense2 + out ----------------
// Block = 4 waves = 16 nodes. Phase 1: each wave aggregates 4 nodes into LDS.
// Phase 2: h2 = relu(a2@Wl2 + h1@Wr2 + b2), 2 col-tiles per wave, h2 -> LDS.
// Phase 3: out = h2@Wo + bo, 1 col-tile per wave. a2 and h2 never touch HBM.

__global__ __launch_bounds__(256)
void k_layer2(const ushort_t* __restrict__ h1h, const ushort_t* __restrict__ h1l,
              const int* __restrict__ off, const ushort_t* __restrict__ col,
              const ushort_t* __restrict__ Wlp, const ushort_t* __restrict__ Wrp,
              const float* __restrict__ b2, const ushort_t* __restrict__ Wop,
              const float* __restrict__ bo, float* __restrict__ out, int n) {
    constexpr int LPR = 16;
    __shared__ ushort_t A2h[16][136];   // stride 136: 2-way bank alias (free)
    __shared__ ushort_t A2l[16][136];
    __shared__ ushort_t H2h[16][136];
    __shared__ ushort_t H2l[16][136];
    int tid = threadIdx.x, waveid = tid >> 6, lane = tid & 63;
    int base = blockIdx.x * 16;
    int li = lane & (LPR - 1);
    int sub = lane / LPR;
    const ushort_t* fbase = h1h + li * 8;

    for (int q = 0; q < 4; ++q) {
        int node = base + waveid * 4 + q;
        int nd = node < n ? node : n - 1;
        int s0 = off[nd], s1 = off[nd + 1];
        float2 a2[4];
        agg_node<128>(fbase, col, s0, s1, sub, a2);
#pragma unroll
        for (int m = LPR; m < 64; m <<= 1) {
#pragma unroll
            for (int j = 0; j < 4; ++j) {
                a2[j].x += __shfl_xor(a2[j].x, m);
                a2[j].y += __shfl_xor(a2[j].y, m);
            }
        }
        if (sub == 0) {
            float inv = 1.f / fmaxf((float)(s1 - s0), 1.f);
            ushort8 vh, vl;
#pragma unroll
            for (int j = 0; j < 4; ++j) {
                float mx = a2[j].x * inv, my = a2[j].y * inv;
                ushort_t hx = bf16_rne(mx), hy = bf16_rne(my);
                vh[2 * j] = hx;     vl[2 * j] = bf16_rne(mx - bf16_to_f(hx));
                vh[2 * j + 1] = hy; vl[2 * j + 1] = bf16_rne(my - bf16_to_f(hy));
            }
            *(ushort8*)&A2h[waveid * 4 + q][li * 8] = vh;
            *(ushort8*)&A2l[waveid * 4 + q][li * 8] = vl;
        }
    }
    __syncthreads();

    // phase 2: h2 tile 16x128, wave computes col-tiles {2*waveid, 2*waveid+1}
    int colq = lane & 15, quad = lane >> 4;
    int arow = colq;
    short8 fah[4], fal[4], fxh[4], fxl[4];
#pragma unroll
    for (int kt = 0; kt < 4; ++kt) {
        fah[kt] = *(const short8*)&A2h[arow][kt * 32 + quad * 8];
        fal[kt] = *(const short8*)&A2l[arow][kt * 32 + quad * 8];
    }
    int grow = base + arow; if (grow >= n) grow = n - 1;
#pragma unroll
    for (int kt = 0; kt < 4; ++kt) {
        fxh[kt] = *(const short8*)(h1h + (size_t)grow * 128 + kt * 32 + quad * 8);
        fxl[kt] = *(const short8*)(h1l + (size_t)grow * 128 + kt * 32 + quad * 8);
    }
    f32x4 acc[2];
#pragma unroll
    for (int t = 0; t < 2; ++t) {
        float bv = b2[(waveid * 2 + t) * 16 + colq];
        acc[t] = (f32x4){bv, bv, bv, bv};
    }
#pragma unroll
    for (int t = 0; t < 2; ++t) {
        int nt = waveid * 2 + t;
#pragma unroll
        for (int kt = 0; kt < 4; ++kt) {
            const ushort_t* pL = Wlp + ((size_t)((kt * 8 + nt) << 6) + lane) * 8;
            acc[t] = mfma3(acc[t], fah[kt], fal[kt],
                           *(const short8*)pL, *(const short8*)(pL + 16384));
            const ushort_t* pR = Wrp + ((size_t)((kt * 8 + nt) << 6) + lane) * 8;
            acc[t] = mfma3(acc[t], fxh[kt], fxl[kt],
                           *(const short8*)pR, *(const short8*)(pR + 16384));
        }
    }
#pragma unroll
    for (int t = 0; t < 2; ++t) {
        int cix = (waveid * 2 + t) * 16 + colq;
#pragma unroll
        for (int r = 0; r < 4; ++r) {
            int row = quad * 4 + r;
            float v = fmaxf(acc[t][r], 0.f);
            ushort_t h = bf16_rne(v);
            H2h[row][cix] = h;
            H2l[row][cix] = bf16_rne(v - bf16_to_f(h));
        }
    }
    __syncthreads();

    // phase 3: out tile 16x64 = h2 @ Wo + bo; wave computes col-tile waveid
    short8 gh[4], gl[4];
#pragma unroll
    for (int kt = 0; kt < 4; ++kt) {
        gh[kt] = *(const short8*)&H2h[arow][kt * 32 + quad * 8];
        gl[kt] = *(const short8*)&H2l[arow][kt * 32 + quad * 8];
    }
    int nt2 = waveid;
    float bv = bo[nt2 * 16 + colq];
    f32x4 acc2 = (f32x4){bv, bv, bv, bv};
#pragma unroll
    for (int kt = 0; kt < 4; ++kt) {
        const ushort_t* p = Wop + ((size_t)((kt * 4 + nt2) << 6) + lane) * 8;
        acc2 = mfma3(acc2, gh[kt], gl[kt],
                     *(const short8*)p, *(const short8*)(p + 8192));
    }
    int rowb = base + quad * 4;
#pragma unroll
    for (int r = 0; r < 4; ++r) {
        int row = rowb + r;
        if (row < n) out[(size_t)row * 64 + nt2 * 16 + colq] = acc2[r];
    }
}

// ---------------- launch ----------------

static inline size_t align256(size_t x) { return (x + 255) & ~(size_t)255; }

extern "C" void kernel_launch(void* const* d_in, const int* in_sizes, int n_in,
                              void* d_out, int out_size, void* d_ws, size_t ws_size,
                              hipStream_t stream) {
    const float* x   = (const float*)d_in[0];
    const int*   ei  = (const int*)d_in[1];
    const float* Wl1 = (const float*)d_in[2];
    const float* bl1 = (const float*)d_in[3];
    const float* Wr1 = (const float*)d_in[4];
    const float* Wl2 = (const float*)d_in[5];
    const float* bl2 = (const float*)d_in[6];
    const float* Wr2 = (const float*)d_in[7];
    const float* Wo  = (const float*)d_in[8];
    const float* bo  = (const float*)d_in[9];

    const int N = in_sizes[0] / 64;   // 50000
    const int E = in_sizes[1] / 2;    // 1600000
    const int* src = ei;
    const int* dst = ei + E;
    const int nbk = (N + BKT_NODES - 1) >> BKT_SHIFT;   // 391 buckets

    // workspace carve
    char* ws = (char*)d_ws;
    int* off = (int*)ws;            ws += align256((size_t)(N + 1) * 4);
    int* bcnt = (int*)ws;           ws += align256((size_t)nbk * 4);
    uint_t* pairs = (uint_t*)ws;    ws += align256((size_t)nbk * BKT_CAP * 4);
    ushort_t* col = (ushort_t*)ws;  ws += align256((size_t)E * 2);
    ushort_t* xh  = (ushort_t*)ws;  ws += align256((size_t)N * 64 * 2);
    ushort_t* xl  = (ushort_t*)ws;  ws += align256((size_t)N * 64 * 2);
    ushort_t* h1h = (ushort_t*)ws;  ws += align256((size_t)N * 128 * 2);
    ushort_t* h1l = (ushort_t*)ws;  ws += align256((size_t)N * 128 * 2);
    ushort_t* Wl1p = (ushort_t*)ws; ws += align256((size_t)2 * 64 * 128 * 2);
    ushort_t* Wr1p = (ushort_t*)ws; ws += align256((size_t)2 * 64 * 128 * 2);
    ushort_t* Wl2p = (ushort_t*)ws; ws += align256((size_t)2 * 128 * 128 * 2);
    ushort_t* Wr2p = (ushort_t*)ws; ws += align256((size_t)2 * 128 * 128 * 2);
    ushort_t* Wop  = (ushort_t*)ws; ws += align256((size_t)2 * 128 * 64 * 2);

    // 1. prep (zero bcnt + split x + pack weights)
    WPack wp;
    wp.srcp[0] = Wl1; wp.dstp[0] = Wl1p; wp.K[0] = 64;  wp.N[0] = 128;
    wp.srcp[1] = Wr1; wp.dstp[1] = Wr1p; wp.K[1] = 64;  wp.N[1] = 128;
    wp.srcp[2] = Wl2; wp.dstp[2] = Wl2p; wp.K[2] = 128; wp.N[2] = 128;
    wp.srcp[3] = Wr2; wp.dstp[3] = Wr2p; wp.K[3] = 128; wp.N[3] = 128;
    wp.srcp[4] = Wo;  wp.dstp[4] = Wop;  wp.K[4] = 128; wp.N[4] = 64;
    int acc_el = 0;
    for (int m = 0; m < 5; ++m) {
        wp.beg[m] = acc_el; acc_el += wp.K[m] * wp.N[m]; wp.end[m] = acc_el;
    }
    int NS = N * 64;
    k_prep<<<(NS + acc_el + 255) / 256, 256, 0, stream>>>(x, xh, xl, NS, wp,
                                                          acc_el, bcnt, nbk);

    // 2. CSR build
    int bbl = (E + EPB - 1) / EPB;
    k_bucket<<<bbl, 1024, 0, stream>>>(src, dst, pairs, bcnt, E, nbk);
    k_csr<<<nbk, 512, 0, stream>>>(pairs, bcnt, off, col, N);

    // 3. layer 1 (agg64 + dense1 fused)
    k_layer1<<<(N + 31) / 32, 256, 0, stream>>>(xh, xl, off, col, Wl1p, Wr1p,
                                                bl1, h1h, h1l, N);

    // 4. layer 2 + output (agg128 + dense2 + out fused)
    k_layer2<<<(N + 15) / 16, 256, 0, stream>>>(h1h, h1l, off, col, Wl2p, Wr2p,
                                                bl2, Wop, bo, (float*)d_out, N);
}